// Round 1
// baseline (1208.709 us; speedup 1.0000x reference)
//
#include <hip/hip_runtime.h>
#include <math.h>

typedef __attribute__((ext_vector_type(8))) short short8;
typedef __attribute__((ext_vector_type(4))) float f32x4;

__device__ __forceinline__ unsigned short bf16_rne(float f) {
  union { float f; unsigned u; } x; x.f = f;
  unsigned r = x.u + 0x7FFFu + ((x.u >> 16) & 1u);
  return (unsigned short)(r >> 16);
}

__device__ __forceinline__ float gelu_f(float x) {
  float z = 0.7978845608028654f * (x + 0.044715f * x * x * x);
  z = fminf(fmaxf(z, -15.f), 15.f);
  float e = __expf(2.f * z);
  float th = (e - 1.f) / (e + 1.f);
  return 0.5f * x * (1.f + th);
}

__device__ __forceinline__ float softplus_f(float x) {
  return (x > 15.f) ? x : log1pf(__expf(x));
}

__device__ __forceinline__ float wave_sum(float v) {
  #pragma unroll
  for (int off = 32; off > 0; off >>= 1) v += __shfl_down(v, off, 64);
  return v;
}

// ---------------- proj: x(8192x32) @ W(32x96) + b -> LN(96) -> gelu -> bf16
__global__ __launch_bounds__(128) void proj_kern(
    const float* __restrict__ x, const float* __restrict__ w,
    const float* __restrict__ b, const float* __restrict__ s,
    const float* __restrict__ o, unsigned short* __restrict__ h0bf)
{
  int row = blockIdx.x, t = threadIdx.x;
  __shared__ float xr[32];
  __shared__ float a1[2], a2[2];
  if (t < 32) xr[t] = x[row * 32 + t];
  __syncthreads();
  float v = 0.f;
  if (t < 96) {
    v = b[t];
    #pragma unroll
    for (int k = 0; k < 32; ++k) v += xr[k] * w[k * 96 + t];
  }
  float c = (t < 96) ? v : 0.f;
  float s1 = wave_sum(c), s2 = wave_sum(c * c);
  int wv = t >> 6, ln = t & 63;
  if (ln == 0) { a1[wv] = s1; a2[wv] = s2; }
  __syncthreads();
  float sum = a1[0] + a1[1], ssq = a2[0] + a2[1];
  float mu = sum / 96.f, var = ssq / 96.f - mu * mu;
  float inv = rsqrtf(var + 1e-5f);
  if (t < 96) {
    float f = (v - mu) * inv * s[t] + o[t];
    h0bf[row * 96 + t] = bf16_rne(gelu_f(f));
  }
}

// ---------------- conv 4x4 SAME over (H=128,W=64,C=96)->192 via 16 shifted MFMA GEMMs
__global__ __launch_bounds__(256) void conv_kern(
    const unsigned short* __restrict__ h0bf, const float* __restrict__ cw,
    const float* __restrict__ cb, float* __restrict__ y)
{
  __shared__ unsigned short As[12 * 64 * 8];
  __shared__ unsigned short Ws[12 * 64 * 8];
  int t = threadIdx.x;
  int i = blockIdx.x;           // image row (= batch index)
  int n0 = blockIdx.y * 64;     // out-channel tile
  int wave = t >> 6, lane = t & 63, quad = lane >> 4, l16 = lane & 15;
  f32x4 zero4 = {0.f, 0.f, 0.f, 0.f};
  f32x4 acc[4];
  #pragma unroll
  for (int nt = 0; nt < 4; ++nt) acc[nt] = zero4;
  for (int tap = 0; tap < 16; ++tap) {
    int kh = tap >> 2, kw = tap & 3;
    int si = i + kh - 1;
    if (si < 0 || si >= 128) continue;   // block-uniform
    {
      int j = t & 63, g = t >> 6;
      int sj = j + kw - 1;
      bool ok = (sj >= 0 && sj < 64);
      #pragma unroll
      for (int q = 0; q < 3; ++q) {
        int kb = g + 4 * q;
        short8 v = {0,0,0,0,0,0,0,0};
        if (ok) v = *(const short8*)(h0bf + (size_t)(si * 64 + sj) * 96 + kb * 8);
        *(short8*)(As + (kb * 64 + j) * 8) = v;
      }
    }
    {
      int n = t & 63, g = t >> 6;
      #pragma unroll
      for (int q = 0; q < 3; ++q) {
        int kb = g + 4 * q;
        short8 v;
        #pragma unroll
        for (int jj = 0; jj < 8; ++jj)
          v[jj] = (short)bf16_rne(cw[((size_t)tap * 96 + kb * 8 + jj) * 192 + n0 + n]);
        *(short8*)(Ws + (kb * 64 + n) * 8) = v;
      }
    }
    __syncthreads();
    #pragma unroll
    for (int ks = 0; ks < 3; ++ks) {
      int kbq = ks * 4 + quad;
      short8 a = *(const short8*)(As + (kbq * 64 + wave * 16 + l16) * 8);
      #pragma unroll
      for (int nt = 0; nt < 4; ++nt) {
        short8 b = *(const short8*)(Ws + (kbq * 64 + nt * 16 + l16) * 8);
        acc[nt] = __builtin_amdgcn_mfma_f32_16x16x32_bf16(a, b, acc[nt], 0, 0, 0);
      }
    }
    __syncthreads();
  }
  #pragma unroll
  for (int nt = 0; nt < 4; ++nt) {
    int col = n0 + nt * 16 + l16;
    float bv = cb[col];
    #pragma unroll
    for (int r = 0; r < 4; ++r) {
      int row = wave * 16 + quad * 4 + r;
      y[(size_t)(i * 64 + row) * 192 + col] = acc[nt][r] + bv;
    }
  }
}

// ---------------- LN(192)+gelu, optional residual; writes fp32 + bf16
__global__ __launch_bounds__(192) void ln_act_kern(
    const float* __restrict__ y, const float* __restrict__ res,
    const float* __restrict__ s, const float* __restrict__ o,
    float* __restrict__ h32, unsigned short* __restrict__ hbf)
{
  int row = blockIdx.x, t = threadIdx.x;
  size_t idx = (size_t)row * 192 + t;
  float v = y[idx];
  if (res) v += res[idx];
  float s1 = wave_sum(v), s2 = wave_sum(v * v);
  __shared__ float a1[3], a2[3];
  int wv = t >> 6, ln = t & 63;
  if (ln == 0) { a1[wv] = s1; a2[wv] = s2; }
  __syncthreads();
  float sum = a1[0] + a1[1] + a1[2];
  float ssq = a2[0] + a2[1] + a2[2];
  float mu = sum * (1.f / 192.f);
  float var = ssq * (1.f / 192.f) - mu * mu;
  float inv = rsqrtf(var + 1e-5f);
  float f = gelu_f((v - mu) * inv * s[t] + o[t]);
  h32[idx] = f;
  hbf[idx] = bf16_rne(f);
}

// ---------------- generic small MFMA GEMM: C = A(bf16) @ W(fp32->bf16) + bias
__global__ __launch_bounds__(256) void gemm_small(
    const unsigned short* __restrict__ A, int lda,
    const float* __restrict__ W, int ldw,
    const float* __restrict__ bias,
    float* __restrict__ outF, unsigned short* __restrict__ outB,
    int K, int ldo, int act)
{
  __shared__ unsigned short As[8 * 64 * 8];
  __shared__ unsigned short Ws[8 * 64 * 8];
  int t = threadIdx.x;
  int m0 = blockIdx.x * 64, n0 = blockIdx.y * 64;
  int wave = t >> 6, lane = t & 63, quad = lane >> 4, l16 = lane & 15;
  f32x4 zero4 = {0.f, 0.f, 0.f, 0.f};
  f32x4 acc[4];
  #pragma unroll
  for (int nt = 0; nt < 4; ++nt) acc[nt] = zero4;
  for (int k0 = 0; k0 < K; k0 += 64) {
    {
      int kb = t & 7, m = t >> 3;
      #pragma unroll
      for (int r = 0; r < 2; ++r) {
        int mm = m + r * 32;
        short8 v = *(const short8*)(A + (size_t)(m0 + mm) * lda + k0 + kb * 8);
        *(short8*)(As + (kb * 64 + mm) * 8) = v;
      }
    }
    {
      int n = t & 63, g = t >> 6;
      #pragma unroll
      for (int q = 0; q < 2; ++q) {
        int kb = g + 4 * q;
        short8 v;
        #pragma unroll
        for (int jj = 0; jj < 8; ++jj)
          v[jj] = (short)bf16_rne(W[(size_t)(k0 + kb * 8 + jj) * ldw + n0 + n]);
        *(short8*)(Ws + (kb * 64 + n) * 8) = v;
      }
    }
    __syncthreads();
    #pragma unroll
    for (int ks = 0; ks < 2; ++ks) {
      short8 a = *(const short8*)(As + ((ks * 4 + quad) * 64 + wave * 16 + l16) * 8);
      #pragma unroll
      for (int nt = 0; nt < 4; ++nt) {
        short8 b = *(const short8*)(Ws + ((ks * 4 + quad) * 64 + nt * 16 + l16) * 8);
        acc[nt] = __builtin_amdgcn_mfma_f32_16x16x32_bf16(a, b, acc[nt], 0, 0, 0);
      }
    }
    __syncthreads();
  }
  #pragma unroll
  for (int nt = 0; nt < 4; ++nt) {
    int col = n0 + nt * 16 + l16;
    float bv = bias[col];
    #pragma unroll
    for (int r = 0; r < 4; ++r) {
      int row = m0 + wave * 16 + quad * 4 + r;
      float v = acc[nt][r] + bv;
      if (act) v = gelu_f(v);
      if (outF) outF[(size_t)row * ldo + col] = v;
      if (outB) outB[(size_t)row * ldo + col] = bf16_rne(v);
    }
  }
}

// ---------------- mass = softplus(h @ mass_w + mass_b), per (row, head)
__global__ __launch_bounds__(256) void mass_kern(
    const float* __restrict__ h32, const float* __restrict__ mw,
    const float* __restrict__ mb, float* __restrict__ outm)
{
  int gid = blockIdx.x * 256 + threadIdx.x;  // 65536
  int row = gid >> 3, hh = gid & 7;
  float acc = mb[hh];
  for (int k = 0; k < 192; ++k) acc += h32[(size_t)row * 192 + k] * mw[k * 8 + hh];
  outm[gid] = softplus_f(acc);
}

// ---------------- gravity attention core per (b, head): S=64, D=24
__global__ __launch_bounds__(256) void attn_core(
    const float* __restrict__ qk, const float* __restrict__ v,
    const float* __restrict__ ms, float* __restrict__ att)
{
  __shared__ float qs[64][25], vs[64][25];
  __shared__ float sqv[64], mm[64], inv64[64];
  __shared__ float sc[64][65];
  int t = threadIdx.x;
  int b = blockIdx.x >> 3, hh = blockIdx.x & 7;
  size_t base = ((size_t)b * 64) * 192 + hh * 24;
  for (int e = t; e < 1536; e += 256) {
    int r = e / 24, d = e - r * 24;
    qs[r][d] = qk[base + (size_t)r * 192 + d];
    vs[r][d] = v[base + (size_t)r * 192 + d];
  }
  __syncthreads();
  if (t < 64) {
    float s = 0.f;
    #pragma unroll
    for (int d = 0; d < 24; ++d) s += qs[t][d] * qs[t][d];
    sqv[t] = s;
    mm[t] = ms[((size_t)b * 64 + t) * 8 + hh];
  }
  __syncthreads();
  {
    int i = t & 63, g = t >> 6;
    float qi[24];
    #pragma unroll
    for (int d = 0; d < 24; ++d) qi[d] = qs[i][d];
    float sqi = sqv[i], mi = mm[i];
    for (int jj = 0; jj < 16; ++jj) {
      int j = g + jj * 4;
      float dot = 0.f;
      #pragma unroll
      for (int d = 0; d < 24; ++d) dot += qi[d] * qs[j][d];
      float d2 = fmaxf(sqi + sqv[j] - 2.f * dot, 0.f) + 1e-6f;
      sc[i][j] = mi * mm[j] / d2;
    }
  }
  __syncthreads();
  if (t < 64) {
    float mx = -1e30f;
    for (int j = 0; j < 64; ++j) mx = fmaxf(mx, sc[t][j]);
    float sum = 0.f;
    for (int j = 0; j < 64; ++j) { float e = __expf(sc[t][j] - mx); sc[t][j] = e; sum += e; }
    inv64[t] = 1.f / sum;
  }
  __syncthreads();
  {
    int i = t & 63, g = t >> 6;
    float a6[6] = {0,0,0,0,0,0};
    for (int j = 0; j < 64; ++j) {
      float w = sc[i][j];
      #pragma unroll
      for (int dd = 0; dd < 6; ++dd) a6[dd] += w * vs[j][g * 6 + dd];
    }
    float inv = inv64[i];
    #pragma unroll
    for (int dd = 0; dd < 6; ++dd)
      att[base + (size_t)i * 192 + g * 6 + dd] = a6[dd] * inv;
  }
}

// ---------------- residual add (post-MLP), writes fp32 + bf16
__global__ __launch_bounds__(256) void resid_kern(
    float* __restrict__ h32, const float* __restrict__ d,
    unsigned short* __restrict__ hbf)
{
  size_t i = (size_t)blockIdx.x * 256 + threadIdx.x;
  float v = h32[i] + d[i];
  h32[i] = v;
  hbf[i] = bf16_rne(v);
}

// ---------------- fc: (128 x 12288) @ (12288 x 12288), split-K=4 partials
__global__ __launch_bounds__(256) void gemm_fc(
    const unsigned short* __restrict__ A, const float* __restrict__ W,
    float* __restrict__ part)
{
  __shared__ unsigned short As[8 * 128 * 8];
  __shared__ unsigned short Ws[8 * 128 * 8];
  int t = threadIdx.x;
  int n0 = blockIdx.x * 128;
  int split = blockIdx.y;
  int wave = t >> 6, lane = t & 63, quad = lane >> 4, l16 = lane & 15;
  int wm = (wave >> 1) * 64, wn = (wave & 1) * 64;
  f32x4 zero4 = {0.f, 0.f, 0.f, 0.f};
  f32x4 acc[4][4];
  #pragma unroll
  for (int mt = 0; mt < 4; ++mt)
    #pragma unroll
    for (int nt = 0; nt < 4; ++nt) acc[mt][nt] = zero4;
  int kend = (split + 1) * 3072;
  for (int k0 = split * 3072; k0 < kend; k0 += 64) {
    {
      int kb = t & 7, m = t >> 3;
      #pragma unroll
      for (int r = 0; r < 4; ++r) {
        int mm2 = m + r * 32;
        short8 vv = *(const short8*)(A + (size_t)mm2 * 12288 + k0 + kb * 8);
        *(short8*)(As + (kb * 128 + mm2) * 8) = vv;
      }
    }
    {
      int n = t & 127, g = t >> 7;
      #pragma unroll
      for (int q = 0; q < 4; ++q) {
        int kb = g * 4 + q;
        short8 vv;
        #pragma unroll
        for (int jj = 0; jj < 8; ++jj)
          vv[jj] = (short)bf16_rne(W[(size_t)(k0 + kb * 8 + jj) * 12288 + n0 + n]);
        *(short8*)(Ws + (kb * 128 + n) * 8) = vv;
      }
    }
    __syncthreads();
    #pragma unroll
    for (int ks = 0; ks < 2; ++ks) {
      short8 a[4], b[4];
      #pragma unroll
      for (int mt = 0; mt < 4; ++mt)
        a[mt] = *(const short8*)(As + ((ks * 4 + quad) * 128 + wm + mt * 16 + l16) * 8);
      #pragma unroll
      for (int nt = 0; nt < 4; ++nt)
        b[nt] = *(const short8*)(Ws + ((ks * 4 + quad) * 128 + wn + nt * 16 + l16) * 8);
      #pragma unroll
      for (int mt = 0; mt < 4; ++mt)
        #pragma unroll
        for (int nt = 0; nt < 4; ++nt)
          acc[mt][nt] = __builtin_amdgcn_mfma_f32_16x16x32_bf16(a[mt], b[nt], acc[mt][nt], 0, 0, 0);
    }
    __syncthreads();
  }
  float* po = part + (size_t)split * 128 * 12288;
  #pragma unroll
  for (int mt = 0; mt < 4; ++mt) {
    #pragma unroll
    for (int nt = 0; nt < 4; ++nt) {
      int col = n0 + wn + nt * 16 + l16;
      #pragma unroll
      for (int r = 0; r < 4; ++r) {
        int row = wm + mt * 16 + quad * 4 + r;
        po[(size_t)row * 12288 + col] = acc[mt][nt][r];
      }
    }
  }
}

// ---------------- reduce split-K partials + bias + gelu
__global__ __launch_bounds__(256) void reduce_fc(
    const float* __restrict__ part, const float* __restrict__ fb,
    float* __restrict__ g)
{
  size_t i = (size_t)blockIdx.x * 256 + threadIdx.x;
  const size_t STRIDE = (size_t)128 * 12288;
  int n = (int)(i % 12288);
  float v = part[i] + part[i + STRIDE] + part[i + 2 * STRIDE] + part[i + 3 * STRIDE] + fb[n];
  g[i] = gelu_f(v);
}

// ---------------- per-row LN(12288) + out matmul (12288 x 24)
__global__ __launch_bounds__(256) void final_kern(
    const float* __restrict__ g, const float* __restrict__ s,
    const float* __restrict__ o, const float* __restrict__ ow,
    const float* __restrict__ ob, float* __restrict__ out)
{
  int m = blockIdx.x, t = threadIdx.x;
  const float* gr = g + (size_t)m * 12288;
  float s1 = 0.f, s2 = 0.f;
  for (int k = t; k < 12288; k += 256) { float v = gr[k]; s1 += v; s2 += v * v; }
  s1 = wave_sum(s1); s2 = wave_sum(s2);
  __shared__ float a1[4], a2[4];
  int wv = t >> 6, ln = t & 63;
  if (ln == 0) { a1[wv] = s1; a2[wv] = s2; }
  __syncthreads();
  float sum = a1[0] + a1[1] + a1[2] + a1[3];
  float ssq = a2[0] + a2[1] + a2[2] + a2[3];
  float mu = sum / 12288.f, var = ssq / 12288.f - mu * mu;
  float inv = rsqrtf(var + 1e-5f);
  float acc[24];
  #pragma unroll
  for (int h = 0; h < 24; ++h) acc[h] = 0.f;
  for (int k = t; k < 12288; k += 256) {
    float f = (gr[k] - mu) * inv * s[k] + o[k];
    const float* wr = ow + (size_t)k * 24;
    #pragma unroll
    for (int h = 0; h < 24; ++h) acc[h] += f * wr[h];
  }
  __shared__ float red[4];
  for (int h = 0; h < 24; ++h) {
    float v = wave_sum(acc[h]);
    __syncthreads();
    if (ln == 0) red[wv] = v;
    __syncthreads();
    if (t == 0) out[m * 24 + h] = red[0] + red[1] + red[2] + red[3] + ob[h];
  }
}

extern "C" void kernel_launch(void* const* d_in, const int* in_sizes, int n_in,
                              void* d_out, int out_size, void* d_ws, size_t ws_size,
                              hipStream_t stream) {
  const float* x      = (const float*)d_in[0];
  const float* proj_w = (const float*)d_in[1];
  const float* proj_b = (const float*)d_in[2];
  const float* ln0_s  = (const float*)d_in[3];
  const float* ln0_o  = (const float*)d_in[4];
  const float* conv_w = (const float*)d_in[5];
  const float* conv_b = (const float*)d_in[6];
  const float* ln1_s  = (const float*)d_in[7];
  const float* ln1_o  = (const float*)d_in[8];
  const float* qk_w   = (const float*)d_in[9];
  const float* qk_b   = (const float*)d_in[10];
  const float* mass_w = (const float*)d_in[11];
  const float* mass_b = (const float*)d_in[12];
  const float* v_w    = (const float*)d_in[13];
  const float* v_b    = (const float*)d_in[14];
  const float* norm_s = (const float*)d_in[15];
  const float* norm_o = (const float*)d_in[16];
  const float* mlp_w1 = (const float*)d_in[17];
  const float* mlp_b1 = (const float*)d_in[18];
  const float* mlp_w2 = (const float*)d_in[19];
  const float* mlp_b2 = (const float*)d_in[20];
  const float* fc_w   = (const float*)d_in[21];
  const float* fc_b   = (const float*)d_in[22];
  const float* ln2_s  = (const float*)d_in[23];
  const float* ln2_o  = (const float*)d_in[24];
  const float* out_w  = (const float*)d_in[25];
  const float* out_b  = (const float*)d_in[26];
  float* out = (float*)d_out;

  char* ws = (char*)d_ws;
  unsigned short* h0bf = (unsigned short*)(ws + 0);            // 1,572,864
  float* h32           = (float*)(ws + 1572864);               // 6,291,456
  unsigned short* hbf  = (unsigned short*)(ws + 7864320);      // 3,145,728
  char* sc = ws + 11010048;                                    // scratch region
  float* t_qk  = (float*)(sc);                                 // 6,291,456
  float* t_v   = (float*)(sc + 6291456);                       // 6,291,456
  float* t_att = (float*)(sc + 12582912);                      // 6,291,456
  unsigned short* hid_bf = (unsigned short*)(sc + 18874368);   // 6,291,456
  float* t_mass = (float*)(sc + 25165824);                     // 262,144
  float* partials = (float*)sc;   // aliases t_qk..hid_bf (dead by fc time)
  float* gbuf = h32;              // aliases h32 (dead by reduce time)

  proj_kern<<<8192, 128, 0, stream>>>(x, proj_w, proj_b, ln0_s, ln0_o, h0bf);
  conv_kern<<<dim3(128, 3), 256, 0, stream>>>(h0bf, conv_w, conv_b, t_att);
  ln_act_kern<<<8192, 192, 0, stream>>>(t_att, nullptr, ln1_s, ln1_o, h32, hbf);
  for (int l = 0; l < 4; ++l) {
    gemm_small<<<dim3(128, 3), 256, 0, stream>>>(hbf, 192, qk_w + l * 36864, 192,
        qk_b + l * 192, t_qk, (unsigned short*)nullptr, 192, 192, 0);
    gemm_small<<<dim3(128, 3), 256, 0, stream>>>(hbf, 192, v_w + l * 36864, 192,
        v_b + l * 192, t_v, (unsigned short*)nullptr, 192, 192, 0);
    mass_kern<<<256, 256, 0, stream>>>(h32, mass_w + l * 1536, mass_b + l * 8, t_mass);
    attn_core<<<1024, 256, 0, stream>>>(t_qk, t_v, t_mass, t_att);
    ln_act_kern<<<8192, 192, 0, stream>>>(t_att, h32, norm_s + l * 192,
                                          norm_o + l * 192, h32, hbf);
  }
  gemm_small<<<dim3(128, 6), 256, 0, stream>>>(hbf, 192, mlp_w1, 384, mlp_b1,
      (float*)nullptr, hid_bf, 192, 384, 1);
  gemm_small<<<dim3(128, 3), 256, 0, stream>>>(hid_bf, 384, mlp_w2, 192, mlp_b2,
      t_att, (unsigned short*)nullptr, 384, 192, 0);
  resid_kern<<<6144, 256, 0, stream>>>(h32, t_att, hbf);
  gemm_fc<<<dim3(96, 4), 256, 0, stream>>>(hbf, fc_w, partials);
  reduce_fc<<<6144, 256, 0, stream>>>(partials, fc_b, gbuf);
  final_kern<<<128, 256, 0, stream>>>(gbuf, ln2_s, ln2_o, out_w, out_b, out);
}

// Round 2
// 1152.070 us; speedup vs baseline: 1.0492x; 1.0492x over previous
//
#include <hip/hip_runtime.h>
#include <math.h>

typedef __attribute__((ext_vector_type(8))) short short8;
typedef __attribute__((ext_vector_type(4))) float f32x4;

__device__ __forceinline__ unsigned short bf16_rne(float f) {
  union { float f; unsigned u; } x; x.f = f;
  unsigned r = x.u + 0x7FFFu + ((x.u >> 16) & 1u);
  return (unsigned short)(r >> 16);
}

__device__ __forceinline__ float gelu_f(float x) {
  float z = 0.7978845608028654f * (x + 0.044715f * x * x * x);
  z = fminf(fmaxf(z, -15.f), 15.f);
  float e = __expf(2.f * z);
  float th = (e - 1.f) / (e + 1.f);
  return 0.5f * x * (1.f + th);
}

__device__ __forceinline__ float softplus_f(float x) {
  return (x > 15.f) ? x : log1pf(__expf(x));
}

__device__ __forceinline__ float wave_sum(float v) {
  #pragma unroll
  for (int off = 32; off > 0; off >>= 1) v += __shfl_down(v, off, 64);
  return v;
}

// ---------------- proj: one wave per row; no barriers
__global__ __launch_bounds__(256) void proj_kern(
    const float* __restrict__ x, const float* __restrict__ w,
    const float* __restrict__ b, const float* __restrict__ s,
    const float* __restrict__ o, unsigned short* __restrict__ h0bf)
{
  int t = threadIdx.x, wave = t >> 6, l = t & 63;
  size_t row = (size_t)blockIdx.x * 4 + wave;
  const float* xr = x + row * 32;
  bool has2 = (l < 32);
  int c1 = l, c2 = has2 ? 64 + l : 0;
  float v1 = b[c1], v2 = b[c2];
  #pragma unroll
  for (int k = 0; k < 32; ++k) {
    float xv = xr[k];
    v1 += xv * w[k * 96 + c1];
    v2 += xv * w[k * 96 + c2];
  }
  if (!has2) v2 = 0.f;
  float sum = wave_sum(v1 + v2);
  float ssq = wave_sum(v1 * v1 + v2 * v2);
  sum = __shfl(sum, 0, 64); ssq = __shfl(ssq, 0, 64);
  float mu = sum / 96.f, var = ssq / 96.f - mu * mu;
  float inv = rsqrtf(var + 1e-5f);
  float f1 = gelu_f((v1 - mu) * inv * s[c1] + o[c1]);
  h0bf[row * 96 + c1] = bf16_rne(f1);
  if (has2) {
    float f2 = gelu_f((v2 - mu) * inv * s[c2] + o[c2]);
    h0bf[row * 96 + c2] = bf16_rne(f2);
  }
}

// ---------------- conv weight pre-convert: cw[tap][ci][co] fp32 -> cwT[tap][co][ci] bf16
__global__ __launch_bounds__(256) void cvtw_kern(
    const float* __restrict__ cw, unsigned short* __restrict__ cwT)
{
  int e = blockIdx.x * 256 + threadIdx.x;       // 294912 total
  int co = e % 192, rest = e / 192;
  int ci = rest % 96, tap = rest / 96;
  cwT[((size_t)tap * 192 + co) * 96 + ci] = bf16_rne(cw[e]);
}

// ---------------- conv 4x4 SAME via 16 shifted MFMA GEMMs, bf16 weights
__global__ __launch_bounds__(256) void conv_kern(
    const unsigned short* __restrict__ h0bf, const unsigned short* __restrict__ cwT,
    const float* __restrict__ cb, float* __restrict__ y)
{
  __shared__ unsigned short As[12 * 64 * 8];
  __shared__ unsigned short Ws[12 * 64 * 8];
  int t = threadIdx.x;
  int i = blockIdx.x;
  int n0 = blockIdx.y * 64;
  int wave = t >> 6, lane = t & 63, quad = lane >> 4, l16 = lane & 15;
  f32x4 zero4 = {0.f, 0.f, 0.f, 0.f};
  f32x4 acc[4];
  #pragma unroll
  for (int nt = 0; nt < 4; ++nt) acc[nt] = zero4;
  for (int tap = 0; tap < 16; ++tap) {
    int kh = tap >> 2, kw = tap & 3;
    int si = i + kh - 1;
    if (si < 0 || si >= 128) continue;
    {
      int j = t & 63, g = t >> 6;
      int sj = j + kw - 1;
      bool ok = (sj >= 0 && sj < 64);
      #pragma unroll
      for (int q = 0; q < 3; ++q) {
        int kb = g + 4 * q;
        short8 v = {0,0,0,0,0,0,0,0};
        if (ok) v = *(const short8*)(h0bf + (size_t)(si * 64 + sj) * 96 + kb * 8);
        *(short8*)(As + (kb * 64 + j) * 8) = v;
      }
    }
    {
      int n = t & 63, g = t >> 6;
      #pragma unroll
      for (int q = 0; q < 3; ++q) {
        int kb = g + 4 * q;
        *(short8*)(Ws + (kb * 64 + n) * 8) =
            *(const short8*)(cwT + ((size_t)tap * 192 + n0 + n) * 96 + kb * 8);
      }
    }
    __syncthreads();
    #pragma unroll
    for (int ks = 0; ks < 3; ++ks) {
      int kbq = ks * 4 + quad;
      short8 a = *(const short8*)(As + (kbq * 64 + wave * 16 + l16) * 8);
      #pragma unroll
      for (int nt = 0; nt < 4; ++nt) {
        short8 b = *(const short8*)(Ws + (kbq * 64 + nt * 16 + l16) * 8);
        acc[nt] = __builtin_amdgcn_mfma_f32_16x16x32_bf16(a, b, acc[nt], 0, 0, 0);
      }
    }
    __syncthreads();
  }
  #pragma unroll
  for (int nt = 0; nt < 4; ++nt) {
    int col = n0 + nt * 16 + l16;
    float bv = cb[col];
    #pragma unroll
    for (int r = 0; r < 4; ++r) {
      int row = wave * 16 + quad * 4 + r;
      y[(size_t)(i * 64 + row) * 192 + col] = acc[nt][r] + bv;
    }
  }
}

// ---------------- LN(192)+gelu: one wave per row, no barriers
__global__ __launch_bounds__(256) void ln_act_kern(
    const float* __restrict__ y, const float* __restrict__ res,
    const float* __restrict__ s, const float* __restrict__ o,
    float* __restrict__ h32, unsigned short* __restrict__ hbf)
{
  int t = threadIdx.x, wave = t >> 6, l = t & 63;
  size_t base = ((size_t)blockIdx.x * 4 + wave) * 192;
  float v0 = y[base + l], v1 = y[base + 64 + l], v2 = y[base + 128 + l];
  if (res) { v0 += res[base + l]; v1 += res[base + 64 + l]; v2 += res[base + 128 + l]; }
  float sum = wave_sum(v0 + v1 + v2);
  float ssq = wave_sum(v0 * v0 + v1 * v1 + v2 * v2);
  sum = __shfl(sum, 0, 64); ssq = __shfl(ssq, 0, 64);
  float mu = sum * (1.f / 192.f);
  float var = ssq * (1.f / 192.f) - mu * mu;
  float inv = rsqrtf(var + 1e-5f);
  float f0 = gelu_f((v0 - mu) * inv * s[l] + o[l]);
  float f1 = gelu_f((v1 - mu) * inv * s[64 + l] + o[64 + l]);
  float f2 = gelu_f((v2 - mu) * inv * s[128 + l] + o[128 + l]);
  h32[base + l] = f0; h32[base + 64 + l] = f1; h32[base + 128 + l] = f2;
  hbf[base + l] = bf16_rne(f0); hbf[base + 64 + l] = bf16_rne(f1); hbf[base + 128 + l] = bf16_rne(f2);
}

// ---------------- fused qk+v projection for one layer
__global__ __launch_bounds__(256) void gemm_qkv(
    const unsigned short* __restrict__ A,
    const float* __restrict__ qw, const float* __restrict__ qb,
    const float* __restrict__ vw, const float* __restrict__ vb,
    float* __restrict__ t_qk, float* __restrict__ t_v)
{
  __shared__ unsigned short As[8 * 64 * 8];
  __shared__ unsigned short Ws[8 * 64 * 8];
  int t = threadIdx.x;
  int m0 = blockIdx.x * 64;
  int ny = blockIdx.y;
  const float* W; const float* bias; float* outF; int n0;
  if (ny < 3) { W = qw; bias = qb; outF = t_qk; n0 = ny * 64; }
  else        { W = vw; bias = vb; outF = t_v;  n0 = (ny - 3) * 64; }
  int wave = t >> 6, lane = t & 63, quad = lane >> 4, l16 = lane & 15;
  f32x4 zero4 = {0.f, 0.f, 0.f, 0.f};
  f32x4 acc[4];
  #pragma unroll
  for (int nt = 0; nt < 4; ++nt) acc[nt] = zero4;
  for (int k0 = 0; k0 < 192; k0 += 64) {
    {
      int kb = t & 7, m = t >> 3;
      #pragma unroll
      for (int r = 0; r < 2; ++r) {
        int mm = m + r * 32;
        *(short8*)(As + (kb * 64 + mm) * 8) =
            *(const short8*)(A + (size_t)(m0 + mm) * 192 + k0 + kb * 8);
      }
    }
    {
      int n = t & 63, g = t >> 6;
      #pragma unroll
      for (int q = 0; q < 2; ++q) {
        int kb = g + 4 * q;
        short8 v;
        #pragma unroll
        for (int jj = 0; jj < 8; ++jj)
          v[jj] = (short)bf16_rne(W[(size_t)(k0 + kb * 8 + jj) * 192 + n0 + n]);
        *(short8*)(Ws + (kb * 64 + n) * 8) = v;
      }
    }
    __syncthreads();
    #pragma unroll
    for (int ks = 0; ks < 2; ++ks) {
      short8 a = *(const short8*)(As + ((ks * 4 + quad) * 64 + wave * 16 + l16) * 8);
      #pragma unroll
      for (int nt = 0; nt < 4; ++nt) {
        short8 b = *(const short8*)(Ws + ((ks * 4 + quad) * 64 + nt * 16 + l16) * 8);
        acc[nt] = __builtin_amdgcn_mfma_f32_16x16x32_bf16(a, b, acc[nt], 0, 0, 0);
      }
    }
    __syncthreads();
  }
  #pragma unroll
  for (int nt = 0; nt < 4; ++nt) {
    int col = n0 + nt * 16 + l16;
    float bv = bias[col];
    #pragma unroll
    for (int r = 0; r < 4; ++r) {
      int row = m0 + wave * 16 + quad * 4 + r;
      outF[(size_t)row * 192 + col] = acc[nt][r] + bv;
    }
  }
}

// ---------------- generic small MFMA GEMM (mlp1 / mlp2+residual)
__global__ __launch_bounds__(256) void gemm_small(
    const unsigned short* __restrict__ A, int lda,
    const float* __restrict__ W, int ldw,
    const float* __restrict__ bias, const float* __restrict__ res,
    float* __restrict__ outF, unsigned short* __restrict__ outB,
    int K, int ldo, int act)
{
  __shared__ unsigned short As[8 * 64 * 8];
  __shared__ unsigned short Ws[8 * 64 * 8];
  int t = threadIdx.x;
  int m0 = blockIdx.x * 64, n0 = blockIdx.y * 64;
  int wave = t >> 6, lane = t & 63, quad = lane >> 4, l16 = lane & 15;
  f32x4 zero4 = {0.f, 0.f, 0.f, 0.f};
  f32x4 acc[4];
  #pragma unroll
  for (int nt = 0; nt < 4; ++nt) acc[nt] = zero4;
  for (int k0 = 0; k0 < K; k0 += 64) {
    {
      int kb = t & 7, m = t >> 3;
      #pragma unroll
      for (int r = 0; r < 2; ++r) {
        int mm = m + r * 32;
        *(short8*)(As + (kb * 64 + mm) * 8) =
            *(const short8*)(A + (size_t)(m0 + mm) * lda + k0 + kb * 8);
      }
    }
    {
      int n = t & 63, g = t >> 6;
      #pragma unroll
      for (int q = 0; q < 2; ++q) {
        int kb = g + 4 * q;
        short8 v;
        #pragma unroll
        for (int jj = 0; jj < 8; ++jj)
          v[jj] = (short)bf16_rne(W[(size_t)(k0 + kb * 8 + jj) * ldw + n0 + n]);
        *(short8*)(Ws + (kb * 64 + n) * 8) = v;
      }
    }
    __syncthreads();
    #pragma unroll
    for (int ks = 0; ks < 2; ++ks) {
      short8 a = *(const short8*)(As + ((ks * 4 + quad) * 64 + wave * 16 + l16) * 8);
      #pragma unroll
      for (int nt = 0; nt < 4; ++nt) {
        short8 b = *(const short8*)(Ws + ((ks * 4 + quad) * 64 + nt * 16 + l16) * 8);
        acc[nt] = __builtin_amdgcn_mfma_f32_16x16x32_bf16(a, b, acc[nt], 0, 0, 0);
      }
    }
    __syncthreads();
  }
  #pragma unroll
  for (int nt = 0; nt < 4; ++nt) {
    int col = n0 + nt * 16 + l16;
    float bv = bias[col];
    #pragma unroll
    for (int r = 0; r < 4; ++r) {
      int row = m0 + wave * 16 + quad * 4 + r;
      float v = acc[nt][r] + bv;
      if (act) v = gelu_f(v);
      if (res) v += res[(size_t)row * ldo + col];
      if (outF) outF[(size_t)row * ldo + col] = v;
      if (outB) outB[(size_t)row * ldo + col] = bf16_rne(v);
    }
  }
}

// ---------------- gravity attention core per (b, head), mass fused in
__global__ __launch_bounds__(256) void attn_core(
    const float* __restrict__ qk, const float* __restrict__ v,
    const float* __restrict__ h32, const float* __restrict__ mw,
    const float* __restrict__ mb, float* __restrict__ att)
{
  __shared__ float qs[64][25], vs[64][25];
  __shared__ float sqv[64], mm[64], inv64[64];
  __shared__ float sc[64][65];
  int t = threadIdx.x;
  int b = blockIdx.x >> 3, hh = blockIdx.x & 7;
  size_t base = ((size_t)b * 64) * 192 + hh * 24;
  for (int e = t; e < 1536; e += 256) {
    int r = e / 24, d = e - r * 24;
    qs[r][d] = qk[base + (size_t)r * 192 + d];
    vs[r][d] = v[base + (size_t)r * 192 + d];
  }
  // mass: 4 threads per row, 48-elem chunks of the 192-dot
  {
    int r = t >> 2, q = t & 3;
    const float* hr = h32 + ((size_t)b * 64 + r) * 192 + q * 48;
    float dot = 0.f;
    #pragma unroll
    for (int kk = 0; kk < 48; ++kk) dot += hr[kk] * mw[(q * 48 + kk) * 8 + hh];
    dot += __shfl_down(dot, 2, 4);
    dot += __shfl_down(dot, 1, 4);
    if (q == 0) mm[r] = softplus_f(dot + mb[hh]);
  }
  __syncthreads();
  if (t < 64) {
    float s = 0.f;
    #pragma unroll
    for (int d = 0; d < 24; ++d) s += qs[t][d] * qs[t][d];
    sqv[t] = s;
  }
  __syncthreads();
  {
    int i = t & 63, g = t >> 6;
    float qi[24];
    #pragma unroll
    for (int d = 0; d < 24; ++d) qi[d] = qs[i][d];
    float sqi = sqv[i], mi = mm[i];
    for (int jj = 0; jj < 16; ++jj) {
      int j = g + jj * 4;
      float dot = 0.f;
      #pragma unroll
      for (int d = 0; d < 24; ++d) dot += qi[d] * qs[j][d];
      float d2 = fmaxf(sqi + sqv[j] - 2.f * dot, 0.f) + 1e-6f;
      sc[i][j] = mi * mm[j] / d2;
    }
  }
  __syncthreads();
  if (t < 64) {
    float mx = -1e30f;
    for (int j = 0; j < 64; ++j) mx = fmaxf(mx, sc[t][j]);
    float sum = 0.f;
    for (int j = 0; j < 64; ++j) { float e = __expf(sc[t][j] - mx); sc[t][j] = e; sum += e; }
    inv64[t] = 1.f / sum;
  }
  __syncthreads();
  {
    int i = t & 63, g = t >> 6;
    float a6[6] = {0,0,0,0,0,0};
    for (int j = 0; j < 64; ++j) {
      float w = sc[i][j];
      #pragma unroll
      for (int dd = 0; dd < 6; ++dd) a6[dd] += w * vs[j][g * 6 + dd];
    }
    float inv = inv64[i];
    #pragma unroll
    for (int dd = 0; dd < 6; ++dd)
      att[base + (size_t)i * 192 + g * 6 + dd] = a6[dd] * inv;
  }
}

// ---------------- fc: (128 x 12288) @ (12288 x 12288), split-K=4, BN=64
// W staged via coalesced float4 loads + in-register bf16 convert + b16 scatter.
__global__ __launch_bounds__(256) void gemm_fc(
    const unsigned short* __restrict__ A, const float* __restrict__ W,
    float* __restrict__ part)
{
  __shared__ unsigned short As[8 * 128 * 8];   // 16 KB
  __shared__ unsigned short Bs[8 * 64 * 8];    // 8 KB
  int t = threadIdx.x;
  int n0 = blockIdx.x * 64;
  int split = blockIdx.y;
  int wave = t >> 6, lane = t & 63, quad = lane >> 4, l16 = lane & 15;
  int wm = wave * 32;
  int a_kb = t & 7, a_m = t >> 3;
  int w_n4 = t & 15, w_kr = t >> 4;
  f32x4 zero4 = {0.f, 0.f, 0.f, 0.f};
  f32x4 acc[2][4];
  #pragma unroll
  for (int mt = 0; mt < 2; ++mt)
    #pragma unroll
    for (int nt = 0; nt < 4; ++nt) acc[mt][nt] = zero4;
  int k0 = split * 3072;
  for (int it = 0; it < 48; ++it, k0 += 64) {
    #pragma unroll
    for (int r = 0; r < 4; ++r) {
      int mm2 = a_m + r * 32;
      *(short8*)(As + (a_kb * 128 + mm2) * 8) =
          *(const short8*)(A + (size_t)mm2 * 12288 + k0 + a_kb * 8);
    }
    #pragma unroll
    for (int r = 0; r < 4; ++r) {
      int k = w_kr + 16 * r;
      f32x4 wv = *(const f32x4*)(W + (size_t)(k0 + k) * 12288 + n0 + w_n4 * 4);
      int kb = k >> 3, kj = k & 7;
      #pragma unroll
      for (int j = 0; j < 4; ++j)
        Bs[(kb * 64 + w_n4 * 4 + j) * 8 + kj] = bf16_rne(wv[j]);
    }
    __syncthreads();
    #pragma unroll
    for (int ks = 0; ks < 2; ++ks) {
      int kq = ks * 4 + quad;
      short8 a[2], b[4];
      #pragma unroll
      for (int mt = 0; mt < 2; ++mt)
        a[mt] = *(const short8*)(As + (kq * 128 + wm + mt * 16 + l16) * 8);
      #pragma unroll
      for (int nt = 0; nt < 4; ++nt)
        b[nt] = *(const short8*)(Bs + (kq * 64 + nt * 16 + l16) * 8);
      #pragma unroll
      for (int mt = 0; mt < 2; ++mt)
        #pragma unroll
        for (int nt = 0; nt < 4; ++nt)
          acc[mt][nt] = __builtin_amdgcn_mfma_f32_16x16x32_bf16(a[mt], b[nt], acc[mt][nt], 0, 0, 0);
    }
    __syncthreads();
  }
  float* po = part + (size_t)split * 128 * 12288;
  #pragma unroll
  for (int mt = 0; mt < 2; ++mt) {
    #pragma unroll
    for (int nt = 0; nt < 4; ++nt) {
      int col = n0 + nt * 16 + l16;
      #pragma unroll
      for (int r = 0; r < 4; ++r) {
        int row = wm + mt * 16 + quad * 4 + r;
        po[(size_t)row * 12288 + col] = acc[mt][nt][r];
      }
    }
  }
}

// ---------------- reduce split-K partials + bias + gelu (float4)
__global__ __launch_bounds__(256) void reduce_fc(
    const float* __restrict__ part, const float* __restrict__ fb,
    float* __restrict__ g)
{
  int i4 = blockIdx.x * 256 + threadIdx.x;       // 393216 float4s
  const int S4 = 128 * 12288 / 4;
  const f32x4* p = (const f32x4*)part;
  f32x4 v = p[i4] + p[i4 + S4] + p[i4 + 2 * S4] + p[i4 + 3 * S4];
  int n = (i4 * 4) % 12288;
  f32x4 bb = *(const f32x4*)(fb + n);
  f32x4 o;
  #pragma unroll
  for (int c = 0; c < 4; ++c) o[c] = gelu_f(v[c] + bb[c]);
  ((f32x4*)g)[i4] = o;
}

// ---------------- per-row LN(12288) + out matmul (12288 x 24)
__global__ __launch_bounds__(256) void final_kern(
    const float* __restrict__ g, const float* __restrict__ s,
    const float* __restrict__ o, const float* __restrict__ ow,
    const float* __restrict__ ob, float* __restrict__ out)
{
  int m = blockIdx.x, t = threadIdx.x;
  const float* gr = g + (size_t)m * 12288;
  float s1 = 0.f, s2 = 0.f;
  for (int k4 = t; k4 < 3072; k4 += 256) {
    f32x4 v = ((const f32x4*)gr)[k4];
    s1 += v[0] + v[1] + v[2] + v[3];
    s2 += v[0]*v[0] + v[1]*v[1] + v[2]*v[2] + v[3]*v[3];
  }
  s1 = wave_sum(s1); s2 = wave_sum(s2);
  __shared__ float a1[4], a2[4];
  int wv = t >> 6, ln = t & 63;
  if (ln == 0) { a1[wv] = s1; a2[wv] = s2; }
  __syncthreads();
  float sum = a1[0] + a1[1] + a1[2] + a1[3];
  float ssq = a2[0] + a2[1] + a2[2] + a2[3];
  float mu = sum / 12288.f, var = ssq / 12288.f - mu * mu;
  float inv = rsqrtf(var + 1e-5f);
  f32x4 acc6[6];
  #pragma unroll
  for (int j = 0; j < 6; ++j) acc6[j] = (f32x4){0.f,0.f,0.f,0.f};
  for (int k = t; k < 12288; k += 256) {
    float f = (gr[k] - mu) * inv * s[k] + o[k];
    const f32x4* owr = (const f32x4*)(ow + (size_t)k * 24);
    #pragma unroll
    for (int j = 0; j < 6; ++j) acc6[j] += f * owr[j];
  }
  __shared__ float red[4][24];
  #pragma unroll
  for (int j = 0; j < 6; ++j)
    #pragma unroll
    for (int c = 0; c < 4; ++c) {
      float v = wave_sum(acc6[j][c]);
      if (ln == 0) red[wv][j * 4 + c] = v;
    }
  __syncthreads();
  if (t < 24) out[m * 24 + t] = red[0][t] + red[1][t] + red[2][t] + red[3][t] + ob[t];
}

extern "C" void kernel_launch(void* const* d_in, const int* in_sizes, int n_in,
                              void* d_out, int out_size, void* d_ws, size_t ws_size,
                              hipStream_t stream) {
  const float* x      = (const float*)d_in[0];
  const float* proj_w = (const float*)d_in[1];
  const float* proj_b = (const float*)d_in[2];
  const float* ln0_s  = (const float*)d_in[3];
  const float* ln0_o  = (const float*)d_in[4];
  const float* conv_w = (const float*)d_in[5];
  const float* conv_b = (const float*)d_in[6];
  const float* ln1_s  = (const float*)d_in[7];
  const float* ln1_o  = (const float*)d_in[8];
  const float* qk_w   = (const float*)d_in[9];
  const float* qk_b   = (const float*)d_in[10];
  const float* mass_w = (const float*)d_in[11];
  const float* mass_b = (const float*)d_in[12];
  const float* v_w    = (const float*)d_in[13];
  const float* v_b    = (const float*)d_in[14];
  const float* norm_s = (const float*)d_in[15];
  const float* norm_o = (const float*)d_in[16];
  const float* mlp_w1 = (const float*)d_in[17];
  const float* mlp_b1 = (const float*)d_in[18];
  const float* mlp_w2 = (const float*)d_in[19];
  const float* mlp_b2 = (const float*)d_in[20];
  const float* fc_w   = (const float*)d_in[21];
  const float* fc_b   = (const float*)d_in[22];
  const float* ln2_s  = (const float*)d_in[23];
  const float* ln2_o  = (const float*)d_in[24];
  const float* out_w  = (const float*)d_in[25];
  const float* out_b  = (const float*)d_in[26];
  float* out = (float*)d_out;

  char* ws = (char*)d_ws;
  unsigned short* h0bf = (unsigned short*)(ws + 0);            // 1,572,864
  float* h32           = (float*)(ws + 1572864);               // 6,291,456
  unsigned short* hbf  = (unsigned short*)(ws + 7864320);      // 3,145,728
  unsigned short* cwT  = (unsigned short*)(ws + 11010048);     // 589,824
  char* sc = ws + 11599872;
  float* t_qk  = (float*)(sc);                                 // 6,291,456
  float* t_v   = (float*)(sc + 6291456);                       // 6,291,456
  float* t_att = (float*)(sc + 12582912);                      // 6,291,456
  unsigned short* hid_bf = (unsigned short*)(sc + 18874368);   // 6,291,456
  float* partials = (float*)sc;   // 25.2 MB, aliases t_qk..hid_bf (dead by fc)
  float* gbuf = h32;              // aliases h32 (dead by reduce time)

  proj_kern<<<2048, 256, 0, stream>>>(x, proj_w, proj_b, ln0_s, ln0_o, h0bf);
  cvtw_kern<<<1152, 256, 0, stream>>>(conv_w, cwT);
  conv_kern<<<dim3(128, 3), 256, 0, stream>>>(h0bf, cwT, conv_b, t_att);
  ln_act_kern<<<2048, 256, 0, stream>>>(t_att, nullptr, ln1_s, ln1_o, h32, hbf);
  for (int l = 0; l < 4; ++l) {
    gemm_qkv<<<dim3(128, 6), 256, 0, stream>>>(hbf, qk_w + l * 36864, qk_b + l * 192,
        v_w + l * 36864, v_b + l * 192, t_qk, t_v);
    attn_core<<<1024, 256, 0, stream>>>(t_qk, t_v, h32, mass_w + l * 1536,
                                        mass_b + l * 8, t_att);
    ln_act_kern<<<2048, 256, 0, stream>>>(t_att, h32, norm_s + l * 192,
                                          norm_o + l * 192, h32, hbf);
  }
  gemm_small<<<dim3(128, 6), 256, 0, stream>>>(hbf, 192, mlp_w1, 384, mlp_b1,
      nullptr, (float*)nullptr, hid_bf, 192, 384, 1);
  gemm_small<<<dim3(128, 3), 256, 0, stream>>>(hid_bf, 384, mlp_w2, 192, mlp_b2,
      h32, h32, hbf, 384, 192, 0);
  gemm_fc<<<dim3(192, 4), 256, 0, stream>>>(hbf, fc_w, partials);
  reduce_fc<<<1536, 256, 0, stream>>>(partials, fc_b, gbuf);
  final_kern<<<128, 256, 0, stream>>>(gbuf, ln2_s, ln2_o, out_w, out_b, out);
}